// Round 1
// baseline (1548.463 us; speedup 1.0000x reference)
//
#include <hip/hip_runtime.h>

// Loihi SNN: 3 layers of (dense GEMM -> Loihi neuron scan -> 1-step delay).
// Layout convention for all activation buffers: [n][c][t], t contiguous.
//
// GEMM: X[n][c][t] = sum_i W[c][i] * S[n][i][t]
// Scan (per neuron, sequential in t):
//   u = trunc(u*0.75) + 64*x_t
//   v = trunc(v*0.96875) + u
//   s = (v >= 5120); v = s ? 0 : v
// Delay: out[t+1] = s[t], out[0] = 0.

#define TT 64   // t-tile
#define TC 64   // c-tile
#define TI 16   // i-tile
#define PAD 4

__global__ __launch_bounds__(256) void gemm_spk(
    const float* __restrict__ S,   // [N][I][T]
    const float* __restrict__ W,   // [Cout][I]
    float* __restrict__ X,         // [N][Cout][T]
    int I, int Cout, int T)
{
    __shared__ float sS[TI][TT + PAD];
    __shared__ float sW[TI][TC + PAD];

    const int n  = blockIdx.z;
    const int t0 = blockIdx.x * TT;
    const int c0 = blockIdx.y * TC;
    const int tid = threadIdx.x;

    const int th_t = tid & 15;   // owns t0 + th_t*4 .. +3
    const int th_c = tid >> 4;   // owns c0 + th_c*4 .. +3

    // staging index precompute
    const int s_ii = tid >> 4;          // 0..15
    const int s_tt = (tid & 15) * 4;    // 0..60
    const int w_c  = tid >> 2;          // 0..63
    const int w_i  = (tid & 3) * 4;     // 0..12

    float acc[4][4] = {{0.f, 0.f, 0.f, 0.f}};

    const float* Sn = S + (size_t)n * I * T;

    const int nChunks = (I + TI - 1) / TI;
    for (int ch = 0; ch < nChunks; ++ch) {
        const int i0 = ch * TI;

        // --- stage S tile [TI][TT] (coalesced float4 along t) ---
        {
            float4 v = make_float4(0.f, 0.f, 0.f, 0.f);
            const int gi = i0 + s_ii;
            const int gt = t0 + s_tt;
            // T % 4 == 0 and s_tt % 4 == 0 -> all-or-nothing per float4
            if (gi < I && gt < T)
                v = *reinterpret_cast<const float4*>(Sn + (size_t)gi * T + gt);
            *reinterpret_cast<float4*>(&sS[s_ii][s_tt]) = v;
        }
        // --- stage W tile transposed into sW[i][c] (coalesced float4 along i) ---
        {
            float4 v = make_float4(0.f, 0.f, 0.f, 0.f);
            const int gi = i0 + w_i;
            const int gc = c0 + w_c;   // Cout multiple of 64 -> always valid
            // I % 4 == 0 and w_i % 4 == 0 -> all-or-nothing per float4
            if (gi < I)
                v = *reinterpret_cast<const float4*>(W + (size_t)gc * I + gi);
            sW[w_i + 0][w_c] = v.x;
            sW[w_i + 1][w_c] = v.y;
            sW[w_i + 2][w_c] = v.z;
            sW[w_i + 3][w_c] = v.w;
        }
        __syncthreads();

        #pragma unroll
        for (int ii = 0; ii < TI; ++ii) {
            const float4 sv = *reinterpret_cast<const float4*>(&sS[ii][th_t * 4]);
            const float4 wv = *reinterpret_cast<const float4*>(&sW[ii][th_c * 4]);
            const float s4[4] = {sv.x, sv.y, sv.z, sv.w};
            const float w4[4] = {wv.x, wv.y, wv.z, wv.w};
            #pragma unroll
            for (int j = 0; j < 4; ++j)
                #pragma unroll
                for (int k = 0; k < 4; ++k)
                    acc[j][k] += s4[j] * w4[k];
        }
        __syncthreads();
    }

    // --- write X[n][c][t], float4 along t per (k) ---
    const int gt = t0 + th_t * 4;
    if (gt < T) {
        #pragma unroll
        for (int k = 0; k < 4; ++k) {
            const int gc = c0 + th_c * 4 + k;
            float4 v = make_float4(acc[0][k], acc[1][k], acc[2][k], acc[3][k]);
            *reinterpret_cast<float4*>(X + ((size_t)n * Cout + gc) * T + gt) = v;
        }
    }
}

__device__ __forceinline__ float loihi_step(float xt, float& u, float& v)
{
    u = truncf(u * 0.75f) + 64.f * xt;       // I_DECAY=1024 -> *3072/4096
    v = truncf(v * 0.96875f) + u;            // V_DECAY=128  -> *3968/4096
    if (v >= 5120.f) { v = 0.f; return 1.f; } // THETA = 80<<6
    return 0.f;
}

// scan layers A+B, write delayed spikes into concatenated combi [n][1024][t]
__global__ void scan_ab(const float* __restrict__ xA,  // [N][512][T]
                        const float* __restrict__ xB,  // [N][512][T]
                        float* __restrict__ combi,     // [N][1024][T]
                        int T)
{
    const int gid = blockIdx.x * blockDim.x + threadIdx.x;
    const int n = gid >> 10;
    const int c = gid & 1023;
    const float* xrow = (c < 512)
        ? xA + ((size_t)n * 512 + c) * T
        : xB + ((size_t)n * 512 + (c - 512)) * T;
    float* crow = combi + ((size_t)n * 1024 + c) * T;

    float u = 0.f, v = 0.f;
    crow[0] = 0.f;
    for (int t = 0; t < T - 1; ++t) {   // last step's spike is discarded by delay
        crow[t + 1] = loihi_step(xrow[t], u, v);
    }
}

__global__ void scan_c(const float* __restrict__ xC,  // [N][256][T]
                       float* __restrict__ out,       // [N][256][T]
                       int T)
{
    const int gid = blockIdx.x * blockDim.x + threadIdx.x;
    const float* xrow = xC + (size_t)gid * T;
    float* orow = out + (size_t)gid * T;

    float u = 0.f, v = 0.f;
    orow[0] = 0.f;
    for (int t = 0; t < T - 1; ++t) {
        orow[t + 1] = loihi_step(xrow[t], u, v);
    }
}

extern "C" void kernel_launch(void* const* d_in, const int* in_sizes, int n_in,
                              void* d_out, int out_size, void* d_ws, size_t ws_size,
                              hipStream_t stream)
{
    const float* tact   = (const float*)d_in[0];  // [32][156][400]
    const float* vis    = (const float*)d_in[1];  // [32][6300][400]
    const float* W_tact = (const float*)d_in[2];  // [512][156]
    const float* W_vis  = (const float*)d_in[3];  // [512][6300]
    const float* W_comb = (const float*)d_in[4];  // [256][1024]
    float* out = (float*)d_out;                   // [32][256][400]

    const int N = 32, T = 400;

    // workspace layout (floats): xA | xB | combi | xC  (~118 MB total)
    float* xA    = (float*)d_ws;                       // [32][512][400]
    float* xB    = xA    + (size_t)N * 512 * T;        // [32][512][400]
    float* combi = xB    + (size_t)N * 512 * T;        // [32][1024][400]
    float* xC    = combi + (size_t)N * 1024 * T;       // [32][256][400]

    const int tTiles = (T + TT - 1) / TT;  // 7

    gemm_spk<<<dim3(tTiles, 512 / TC, N), 256, 0, stream>>>(tact, W_tact, xA, 156, 512, T);
    gemm_spk<<<dim3(tTiles, 512 / TC, N), 256, 0, stream>>>(vis,  W_vis,  xB, 6300, 512, T);
    scan_ab<<<dim3((N * 1024) / 64), 64, 0, stream>>>(xA, xB, combi, T);
    gemm_spk<<<dim3(tTiles, 256 / TC, N), 256, 0, stream>>>(combi, W_comb, xC, 1024, 256, T);
    scan_c<<<dim3((N * 256) / 64), 64, 0, stream>>>(xC, out, T);
}

// Round 2
// 769.561 us; speedup vs baseline: 2.0121x; 2.0121x over previous
//
#include <hip/hip_runtime.h>

// Loihi SNN, 3 layers of (GEMM -> Loihi scan -> delay), MFMA edition.
//
// Exact-fp32-via-bf16 trick: spikes are {0,1} (exact in bf16); W splits
// EXACTLY into 3 bf16 planes (hi/mid/lo). GEMM = 3 bf16 MFMA passes
// accumulated into one fp32 acc -> exact products, fp32-ordered sums.
//
// Layouts:
//   S''  (GEMM B operand): [nt = n*400+t][Kpad] bf16(u16), contiguous K
//   W3   (GEMM A operand): 3 planes [C][Kpad] bf16(u16)
//   X    (GEMM out):       [nt][C] fp32  -> scans read coalesced per t
//   out:                   [n][c][t] fp32 (reference layout)

typedef unsigned short u16;
typedef unsigned int u32;
typedef __attribute__((ext_vector_type(8))) short short8;
typedef __attribute__((ext_vector_type(4))) float f32x4;

#define GLOAD16(g, l)                                                         \
    __builtin_amdgcn_global_load_lds(                                         \
        (const __attribute__((address_space(1))) u32*)(g),                    \
        (__attribute__((address_space(3))) u32*)(l), 16, 0, 0)

__device__ __forceinline__ u16 f2bf_trunc(float x) {
    return (u16)(__float_as_uint(x) >> 16);
}

// ---------------- W -> 3 exact bf16 planes ----------------
__global__ void split_w(const float* __restrict__ W,
                        u16* __restrict__ Wh, u16* __restrict__ Wm,
                        u16* __restrict__ Wl, int K, int Kpad)
{
    const int c = blockIdx.y;
    const int k = blockIdx.x * 256 + threadIdx.x;
    if (k >= Kpad) return;
    float w = (k < K) ? W[(size_t)c * K + k] : 0.f;
    u32 b  = __float_as_uint(w);
    u32 hb = b & 0xFFFF0000u;
    float r  = w - __uint_as_float(hb);
    u32 mb = __float_as_uint(r) & 0xFFFF0000u;
    float r2 = r - __uint_as_float(mb);
    u32 lb = __float_as_uint(r2) & 0xFFFF0000u;
    size_t o = (size_t)c * Kpad + k;
    Wh[o] = (u16)(hb >> 16);
    Wm[o] = (u16)(mb >> 16);
    Wl[o] = (u16)(lb >> 16);
}

// ------- spikes fp32 [n][I][400] -> bf16 [n*400+t][Kpad] (transpose) -------
__global__ __launch_bounds__(256) void cvt_sp(const float* __restrict__ S,
                                              u16* __restrict__ Sp,
                                              int I, int Kpad)
{
    __shared__ u16 tile[64][80];   // [t][i], stride 160B (16B-aligned rows)
    const int n  = blockIdx.z;
    const int i0 = blockIdx.y * 64;
    const int t0 = blockIdx.x * 64;
    const int tid = threadIdx.x;

    const int il = tid >> 2;       // 0..63 input row (i)
    const int tq = tid & 3;
    const int gi = i0 + il;
    const bool iok = gi < I;
    const float* srow = S + ((size_t)n * I + gi) * 400 + t0;

    #pragma unroll
    for (int s = 0; s < 4; ++s) {
        const int tl = tq * 16 + s * 4;
        float4 v = make_float4(0.f, 0.f, 0.f, 0.f);
        if (iok && (t0 + tl) < 400)
            v = *(const float4*)(srow + tl);
        tile[tl + 0][il] = f2bf_trunc(v.x);
        tile[tl + 1][il] = f2bf_trunc(v.y);
        tile[tl + 2][il] = f2bf_trunc(v.z);
        tile[tl + 3][il] = f2bf_trunc(v.w);
    }
    __syncthreads();

    const int tl = tid >> 2;       // 0..63 output row (t)
    const int iq = tid & 3;        // 16-wide i chunk
    const int t  = t0 + tl;
    const int go = i0 + iq * 16;
    if (t < 400 && go < Kpad) {
        u16* dst = Sp + (size_t)(n * 400 + t) * Kpad + go;
        *(short8*)(dst)     = *(const short8*)&tile[tl][iq * 16];
        *(short8*)(dst + 8) = *(const short8*)&tile[tl][iq * 16 + 8];
    }
}

// ---------------- 3-plane bf16 MFMA GEMM ----------------
// X[nt][c] = sum_k (Wh+Wm+Wl)[c][k] * S[nt][k]
// 128x128 tile, BK=32, 4 waves (2x2), wave = 64x64 = 4x4 MFMA tiles.
__global__ __launch_bounds__(256) void gemm3(
    const u16* __restrict__ Wh, const u16* __restrict__ Wm,
    const u16* __restrict__ Wl, const u16* __restrict__ S,
    float* __restrict__ X, int C, int Kpad)
{
    __shared__ u16 lds[4 * 4096];   // A planes 0..2, B at 3*4096 ([128][32] each)

    const int tid  = threadIdx.x;
    const int lane = tid & 63, wave = tid >> 6;
    const int c0  = blockIdx.y * 128;
    const int nt0 = blockIdx.x * 128;

    // staging: per wave 2 chunks per tile; chunk = 16 rows x 32 k (1KB)
    const int ch0 = wave * 2, ch1 = ch0 + 1;
    const int lrow = lane >> 2;          // row within chunk
    const int lk   = (lane & 3) * 8;     // u16 offset within row
    const size_t aoff0 = (size_t)(c0 + ch0 * 16 + lrow) * Kpad + lk;
    const size_t aoff1 = (size_t)(c0 + ch1 * 16 + lrow) * Kpad + lk;
    const size_t boff0 = (size_t)(nt0 + ch0 * 16 + lrow) * Kpad + lk;
    const size_t boff1 = (size_t)(nt0 + ch1 * 16 + lrow) * Kpad + lk;

    const int l15 = lane & 15, l16 = lane >> 4;
    const int wm = wave >> 1, wn = wave & 1;
    const int aBase = (wm * 64 + l15) * 32 + l16 * 8;            // + p*4096 + mi*512
    const int bBase = 3 * 4096 + (wn * 64 + l15) * 32 + l16 * 8; // + ni*512

    f32x4 acc[4][4];
    #pragma unroll
    for (int i = 0; i < 4; ++i)
        #pragma unroll
        for (int j = 0; j < 4; ++j)
            acc[i][j] = {0.f, 0.f, 0.f, 0.f};

    const u16* Wp[3] = {Wh, Wm, Wl};

    for (int k0 = 0; k0 < Kpad; k0 += 32) {
        #pragma unroll
        for (int p = 0; p < 3; ++p) {
            GLOAD16(Wp[p] + aoff0 + k0, &lds[p * 4096 + ch0 * 512]);
            GLOAD16(Wp[p] + aoff1 + k0, &lds[p * 4096 + ch1 * 512]);
        }
        GLOAD16(S + boff0 + k0, &lds[3 * 4096 + ch0 * 512]);
        GLOAD16(S + boff1 + k0, &lds[3 * 4096 + ch1 * 512]);
        __syncthreads();   // drains vmcnt -> staged data visible

        short8 bf[4];
        #pragma unroll
        for (int ni = 0; ni < 4; ++ni)
            bf[ni] = *(const short8*)&lds[bBase + ni * 512];
        #pragma unroll
        for (int mi = 0; mi < 4; ++mi) {
            #pragma unroll
            for (int p = 0; p < 3; ++p) {
                short8 af = *(const short8*)&lds[p * 4096 + aBase + mi * 512];
                #pragma unroll
                for (int ni = 0; ni < 4; ++ni)
                    acc[mi][ni] = __builtin_amdgcn_mfma_f32_16x16x32_bf16(
                        af, bf[ni], acc[mi][ni], 0, 0, 0);
            }
        }
        __syncthreads();   // readers done before next overwrite
    }

    // epilogue: D row=(l16*4+r) -> c, col=l15 -> nt ; 4 consecutive c = float4
    #pragma unroll
    for (int mi = 0; mi < 4; ++mi) {
        const int c = c0 + wm * 64 + mi * 16 + l16 * 4;
        #pragma unroll
        for (int ni = 0; ni < 4; ++ni) {
            const int nt = nt0 + wn * 64 + ni * 16 + l15;
            *(f32x4*)&X[(size_t)nt * C + c] = acc[mi][ni];
        }
    }
}

// ---------------- Loihi scans (8-deep pipelined loads) ----------------
__global__ __launch_bounds__(256) void scan_ab(const float* __restrict__ Xt,
                                               const float* __restrict__ Xv,
                                               u16* __restrict__ Sc)
{
    const int gid = blockIdx.x * 256 + threadIdx.x;   // 32*1024 threads
    const int n = gid >> 10;
    const int c = gid & 1023;
    const float* xrow = (c < 512)
        ? (Xt + (size_t)(n * 400) * 512 + c)
        : (Xv + (size_t)(n * 400) * 512 + (c - 512));
    u16* srow = Sc + (size_t)(n * 400) * 1024 + c;
    srow[0] = 0;   // delay: t=0 is zero

    float buf[8];
    #pragma unroll
    for (int d = 0; d < 8; ++d) buf[d] = xrow[(size_t)d * 512];
    float u = 0.f, v = 0.f;
    #pragma unroll 8
    for (int t = 0; t < 400; ++t) {
        const float xt = buf[t & 7];
        const int tn = t + 8;
        buf[t & 7] = (tn < 400) ? xrow[(size_t)tn * 512] : 0.f;
        u = truncf(u * 0.75f) + 64.f * xt;
        v = truncf(v * 0.96875f) + u;
        float sp = 0.f;
        if (v >= 5120.f) { sp = 1.f; v = 0.f; }
        if (t < 399) srow[(size_t)(t + 1) * 1024] = (sp != 0.f) ? (u16)0x3F80 : (u16)0;
    }
}

__global__ __launch_bounds__(256) void scan_c(const float* __restrict__ Xc,
                                              float* __restrict__ out)
{
    const int gid = blockIdx.x * 256 + threadIdx.x;   // 32*256 threads
    const int n = gid >> 8;
    const int c = gid & 255;
    const float* xrow = Xc + (size_t)(n * 400) * 256 + c;
    float* orow = out + ((size_t)n * 256 + c) * 400;
    orow[0] = 0.f;

    float buf[8];
    #pragma unroll
    for (int d = 0; d < 8; ++d) buf[d] = xrow[(size_t)d * 256];
    float u = 0.f, v = 0.f;
    #pragma unroll 8
    for (int t = 0; t < 400; ++t) {
        const float xt = buf[t & 7];
        const int tn = t + 8;
        buf[t & 7] = (tn < 400) ? xrow[(size_t)tn * 256] : 0.f;
        u = truncf(u * 0.75f) + 64.f * xt;
        v = truncf(v * 0.96875f) + u;
        float sp = 0.f;
        if (v >= 5120.f) { sp = 1.f; v = 0.f; }
        if (t < 399) orow[t + 1] = sp;
    }
}

extern "C" void kernel_launch(void* const* d_in, const int* in_sizes, int n_in,
                              void* d_out, int out_size, void* d_ws, size_t ws_size,
                              hipStream_t stream)
{
    const float* tact   = (const float*)d_in[0];  // [32][156][400]
    const float* vis    = (const float*)d_in[1];  // [32][6300][400]
    const float* W_tact = (const float*)d_in[2];  // [512][156]
    const float* W_vis  = (const float*)d_in[3];  // [512][6300]
    const float* W_comb = (const float*)d_in[4];  // [256][1024]
    float* out = (float*)d_out;                   // [32][256][400]

    const int NT = 32 * 400;            // 12800
    const int Kt = 156, Ktp = 160;
    const int Kv = 6300, Kvp = 6304;
    const int Kc = 1024;

    // ---- workspace carve-up (bytes, all 256-aligned) ≈ 239.4 MB ----
    char* p = (char*)d_ws;
    u16* Sv = (u16*)p;                 p += (size_t)NT * Kvp * 2;     // 161.4MB
    u16* St = (u16*)p;                 p += (size_t)NT * Ktp * 2;     //   4.1MB
    u16* Wt_h = (u16*)p;               p += (size_t)512 * Ktp * 2;
    u16* Wt_m = (u16*)p;               p += (size_t)512 * Ktp * 2;
    u16* Wt_l = (u16*)p;               p += (size_t)512 * Ktp * 2;
    u16* Wv_h = (u16*)p;               p += (size_t)512 * Kvp * 2;
    u16* Wv_m = (u16*)p;               p += (size_t)512 * Kvp * 2;
    u16* Wv_l = (u16*)p;               p += (size_t)512 * Kvp * 2;
    u16* Wc_h = (u16*)p;               p += (size_t)256 * Kc * 2;
    u16* Wc_m = (u16*)p;               p += (size_t)256 * Kc * 2;
    u16* Wc_l = (u16*)p;               p += (size_t)256 * Kc * 2;
    float* Xt = (float*)p;             p += (size_t)NT * 512 * 4;     //  26.2MB
    float* Xv = (float*)p;             p += (size_t)NT * 512 * 4;     //  26.2MB
    // aliases (lifetimes disjoint in stream order):
    u16*   Sc = Sv;     // combi spikes [NT][1024] bf16, after Sv is dead
    float* Xc = Xt;     // combi GEMM out [NT][256], after Xt is dead

    // 1) weight splits
    split_w<<<dim3((Ktp + 255) / 256, 512), 256, 0, stream>>>(W_tact, Wt_h, Wt_m, Wt_l, Kt, Ktp);
    split_w<<<dim3((Kvp + 255) / 256, 512), 256, 0, stream>>>(W_vis,  Wv_h, Wv_m, Wv_l, Kv, Kvp);
    split_w<<<dim3((Kc  + 255) / 256, 256), 256, 0, stream>>>(W_comb, Wc_h, Wc_m, Wc_l, Kc, Kc);

    // 2) spike transpose+convert
    cvt_sp<<<dim3(7, (Ktp + 63) / 64, 32), 256, 0, stream>>>(tact, St, Kt, Ktp);
    cvt_sp<<<dim3(7, (Kvp + 63) / 64, 32), 256, 0, stream>>>(vis,  Sv, Kv, Kvp);

    // 3) layer GEMMs + scans
    gemm3<<<dim3(NT / 128, 512 / 128), 256, 0, stream>>>(Wt_h, Wt_m, Wt_l, St, Xt, 512, Ktp);
    gemm3<<<dim3(NT / 128, 512 / 128), 256, 0, stream>>>(Wv_h, Wv_m, Wv_l, Sv, Xv, 512, Kvp);
    scan_ab<<<dim3((32 * 1024) / 256), 256, 0, stream>>>(Xt, Xv, Sc);
    gemm3<<<dim3(NT / 128, 256 / 128), 256, 0, stream>>>(Wc_h, Wc_m, Wc_l, Sc, Xc, 256, Kc);
    scan_c<<<dim3((32 * 256) / 256), 256, 0, stream>>>(Xc, out);

    (void)in_sizes; (void)n_in; (void)out_size; (void)ws_size;
}